// Round 14
// baseline (235.741 us; speedup 1.0000x reference)
//
#include <hip/hip_runtime.h>
#include <hip/hip_bf16.h>

typedef unsigned short u16;
typedef unsigned int u32;

typedef __bf16 bf16x8 __attribute__((ext_vector_type(8)));
typedef float f32x4 __attribute__((ext_vector_type(4)));

#define NEG_SLOPE 0.2f
#define CAP 5120

__device__ __forceinline__ float bf2f(u16 u){
  union { u32 i; float f; } c; c.i = ((u32)u) << 16; return c.f;
}
__device__ __forceinline__ u16 f2bf(float f){
  __hip_bfloat16 h = __float2bfloat16(f);
  u16 u; __builtin_memcpy(&u, &h, 2); return u;
}
__device__ __forceinline__ u32 pack2(float a, float b){
  return (u32)f2bf(a) | ((u32)f2bf(b) << 16);
}
__device__ __forceinline__ float2 bfpair(u32 v){
  union { u32 i; float f; } a, b;
  a.i = v << 16; b.i = v & 0xffff0000u;
  return make_float2(a.f, b.f);
}
__device__ __forceinline__ float lrelu(float x){
  return fmaxf(x, 0.f) + NEG_SLOPE * fminf(x, 0.f);
}
__device__ __forceinline__ float eluf(float x){
  return x > 0.f ? x : (__expf(x) - 1.f);
}
__device__ __forceinline__ bf16x8 ld_frag(const uint4* p){
  uint4 u = *p;
  bf16x8 r;
  __builtin_memcpy(&r, &u, 16);
  return r;
}

// ---------------- dtype probe ----------------
__global__ void k_probe(const u16* __restrict__ w, int* __restrict__ flag){
  int t = threadIdx.x;
  int hit = 0;
  for (int i = t; i < 4096; i += 64){
    u16 v = w[i];
    int e = (v >> 7) & 0xFF;
    if (e >= 200) hit = 1;
  }
  unsigned long long b = __ballot(hit);
  if (t == 0) flag[0] = b ? 1 : 0;   // 1 => float32 data
}

// ---------------- param conversion to f32 arena ----------------
struct Params13 {
  const void* src[13];
  int off[13];
  int n[13];
};

__global__ void k_cvt(Params13 P, const int* __restrict__ flag, float* __restrict__ dst){
  int t = blockIdx.y;
  int i = blockIdx.x*256 + threadIdx.x;
  if (i >= P.n[t]) return;
  int f = flag[0];
  float v = f ? ((const float*)P.src[t])[i] : bf2f(((const u16*)P.src[t])[i]);
  dst[P.off[t] + i] = v;
}

// ---------------- pre-pack W2s/W2d/Wc into MFMA B-fragment order (bf16) ----------------
__global__ void k_wprep(const float* __restrict__ pr, u16* __restrict__ wp){
  int g = blockIdx.x*256 + threadIdx.x;   // 0..49151
  if (g >= 3*16384) return;
  int m = g >> 14;
  int e = g & 16383;
  int j    = e & 7;
  int lane = (e >> 3) & 63;
  int kb   = (e >> 9) & 3;
  int nt   = (e >> 11) & 7;
  int k = kb*32 + (lane >> 4)*8 + j;
  int n = nt*16 + (lane & 15);
  const int Woff[3] = {37120, 53504, 70144};
  wp[g] = f2bf(pr[Woff[m] + k*128 + n]);
}

// pack block-diagonal B from Ts
__global__ void k_t1prep(const float* __restrict__ Ts, u16* __restrict__ tp){
  int g = blockIdx.x*256 + threadIdx.x;   // 0..16383
  if (g >= 16384) return;
  int j    = g & 7;
  int lane = (g >> 3) & 63;
  int kb   = (g >> 9) & 3;
  int nt   = (g >> 11) & 7;
  int k = kb*32 + (lane >> 4)*8 + j;
  int n = nt*16 + (lane & 15);
  int h = k >> 5, hp = n >> 5, v = k & 31;
  tp[g] = (h == hp) ? f2bf(Ts[v*128 + n]) : (u16)0;
}

// ---------------- bucketed CSR build ----------------
__global__ __launch_bounds__(256) void k_bin(
    const int* __restrict__ src, const int* __restrict__ dst, const int* __restrict__ vf,
    int* __restrict__ gcnt, u32* __restrict__ bbuf, int E){
  __shared__ int lcnt[256];
  __shared__ int lloc[256];
  int t = threadIdx.x;
  lcnt[t] = 0;
  __syncthreads();
  int base = blockIdx.x*2048;
  int s[8], d[8];
  #pragma unroll
  for (int k=0;k<8;++k){
    int i = base + k*256 + t;
    if (i < E){ s[k]=src[i]; d[k]=dst[i]; atomicAdd(&lcnt[d[k]>>8], 1); }
    else s[k] = -1;
  }
  __syncthreads();
  if (lcnt[t] > 0) lloc[t] = atomicAdd(&gcnt[t], lcnt[t]);
  __syncthreads();
  #pragma unroll
  for (int k=0;k<8;++k){
    if (s[k] >= 0){
      int b = d[k]>>8;
      int pos = atomicAdd(&lloc[b], 1);
      if (pos < CAP)
        bbuf[(size_t)b*CAP + pos] = ((u32)s[k]<<13) | ((u32)vf[s[k]]<<8) | (u32)(d[k]&255);
    }
  }
}

__global__ __launch_bounds__(256) void k_bcnt(
    const u32* __restrict__ bbuf, const int* __restrict__ gcnt,
    u32* __restrict__ H, int* __restrict__ deg, int N){
  __shared__ u32 lh[8192];   // 256 nodes x 32 types
  __shared__ int ldeg[256];
  int b = blockIdx.x;
  int t = threadIdx.x;
  for (int i=t;i<8192;i+=256) lh[i]=0;
  ldeg[t]=0;
  __syncthreads();
  int n = gcnt[b]; if (n > CAP) n = CAP;
  const u32* bb = bbuf + (size_t)b*CAP;
  for (int i=t;i<n;i+=256){
    u32 it = bb[i];
    int ld = it & 255, v = (it>>8)&31;
    atomicAdd(&lh[ld*32+v], 1u);
    atomicAdd(&ldeg[ld], 1);
  }
  __syncthreads();
  int node0 = b*256;
  for (int i=t;i<8192;i+=256){
    int ld = i>>5;
    if (node0+ld < N) H[(size_t)(node0+ld)*32 + (i&31)] = lh[i];
  }
  if (node0+t < N) deg[node0+t] = ldeg[t];
}

__global__ __launch_bounds__(256) void k_csort(
    const u32* __restrict__ bbuf, const int* __restrict__ gcnt,
    const int* __restrict__ rowptr, int* __restrict__ esrc, int N){
  __shared__ int cur[256];
  int b = blockIdx.x;
  int t = threadIdx.x;
  int node0 = b*256;
  cur[t] = (node0+t < N) ? rowptr[node0+t] : 0;
  __syncthreads();
  int n = gcnt[b]; if (n > CAP) n = CAP;
  const u32* bb = bbuf + (size_t)b*CAP;
  for (int i=t;i<n;i+=256){
    u32 it = bb[i];
    int ld = it & 255;
    int pos = atomicAdd(&cur[ld], 1);
    esrc[pos] = (int)(it >> 13);
  }
}

// ---------------- scan (deg -> rowptr) ----------------
__global__ __launch_bounds__(256) void k_bsum(const int* __restrict__ deg,
                                              int* __restrict__ bsum, int N){
  __shared__ int ws[4];
  int t = threadIdx.x;
  int i = blockIdx.x*256 + t;
  int v = (i < N) ? deg[i] : 0;
  #pragma unroll
  for (int off=32; off>=1; off>>=1) v += __shfl_down(v, off);
  if ((t & 63) == 0) ws[t>>6] = v;
  __syncthreads();
  if (t == 0) bsum[blockIdx.x] = ws[0]+ws[1]+ws[2]+ws[3];
}

__global__ void k_scanb(const int* __restrict__ bsum, int* __restrict__ boff,
                        int* __restrict__ rowptr, int nb, int N){
  int l = threadIdx.x;
  int carry = 0;
  int nChunk = (nb + 63) >> 6;
  for (int c = 0; c < nChunk; ++c){
    int idx = (c << 6) + l;
    int v = (idx < nb) ? bsum[idx] : 0;
    int x = v;
    #pragma unroll
    for (int off=1; off<64; off<<=1){
      int y = __shfl_up(x, off);
      if (l >= off) x += y;
    }
    if (idx < nb) boff[idx] = carry + x - v;
    carry += __shfl(x, 63);
  }
  if (l == 0) rowptr[N] = carry;
}

__global__ __launch_bounds__(256) void k_scan2(const int* __restrict__ deg,
                                               const int* __restrict__ boff,
                                               int* __restrict__ rowptr, int N){
  __shared__ int ws[4];
  int t = threadIdx.x;
  int i = blockIdx.x*256 + t;
  int lane = t & 63, wid = t >> 6;
  int v = (i < N) ? deg[i] : 0;
  int x = v;
  #pragma unroll
  for (int off=1; off<64; off<<=1){
    int y = __shfl_up(x, off);
    if (lane >= off) x += y;
  }
  if (lane == 63) ws[wid] = x;
  __syncthreads();
  int woff = 0;
  #pragma unroll
  for (int w=0; w<4; ++w) woff += (w < wid) ? ws[w] : 0;
  int excl = boff[blockIdx.x] + woff + x - v;
  if (i < N) rowptr[i] = excl;
}

// ---------------- layer-1 tiny tables (16 blocks each) ----------------
__global__ void k_tinyA(const float* __restrict__ pr,
                        float* __restrict__ Ts, float* __restrict__ Td){
  const float* emb = pr + 0;
  const float* W1s = pr + 4096;
  const float* W1d = pr + 20480;
  int g = blockIdx.x*256 + threadIdx.x;   // 0..4095
  int v = g >> 7, j = g & 127;
  float as = 0.f, ad = 0.f;
  for (int k = 0; k < 128; ++k){
    float e = emb[v*128 + k];
    as += e * W1s[k*128 + j];
    ad += e * W1d[k*128 + j];
  }
  Ts[g] = as; Td[g] = ad;
}

__global__ void k_tinyB(const float* __restrict__ Ts, const float* __restrict__ Td,
                        const float* __restrict__ pr, float* __restrict__ S1){
  const float* a1 = pr + 36864;
  int g = blockIdx.x*256 + threadIdx.x;   // vd*128 + vs*4 + h
  int vd = g >> 7, vs = (g >> 2) & 31, h = g & 3;
  float acc = 0.f;
  for (int dd = 0; dd < 32; ++dd){
    float x = Ts[vs*128 + h*32 + dd] + Td[vd*128 + h*32 + dd];
    acc += a1[h*32 + dd] * lrelu(x);
  }
  S1[g] = acc;
}

__global__ void k_tinyC(const float* __restrict__ S1, float* __restrict__ Ee){
  int g = blockIdx.x*256 + threadIdx.x;
  int vd = g >> 7, h = g & 3;
  float M = -INFINITY;
  #pragma unroll 8
  for (int vs = 0; vs < 32; ++vs) M = fmaxf(M, S1[vd*128 + vs*4 + h]);
  Ee[g] = __expf(S1[g] - M);
}

// ---------------- node1 weights: Wn[d][h*32+v] = cnt*Ee / sum (bf16) ----------------
__global__ __launch_bounds__(256) void k_node1w(
    const u32* __restrict__ H, const int* __restrict__ vf,
    const float* __restrict__ Ee, u16* __restrict__ wnb, int N){
  int t = threadIdx.x;
  int wid = t >> 6, lane = t & 63;
  int base = blockIdx.x * 32;
  for (int dd = wid; dd < 32; dd += 4){
    int d = base + dd;
    if (d >= N) break;
    int tt = vf[d];
    float4 w4 = make_float4(0.f,0.f,0.f,0.f);
    if (lane < 32){
      float cf = (float)H[(size_t)d*32 + lane];
      const float4 e4 = *reinterpret_cast<const float4*>(Ee + tt*128 + lane*4);
      w4.x = cf*e4.x; w4.y = cf*e4.y; w4.z = cf*e4.z; w4.w = cf*e4.w;
    }
    float4 sv = w4;
    #pragma unroll
    for (int off=1; off<32; off<<=1){
      sv.x += __shfl_xor(sv.x, off);
      sv.y += __shfl_xor(sv.y, off);
      sv.z += __shfl_xor(sv.z, off);
      sv.w += __shfl_xor(sv.w, off);
    }
    if (lane < 32){
      float ix = (sv.x > 0.f) ? 1.f/sv.x : 0.f;
      float iy = (sv.y > 0.f) ? 1.f/sv.y : 0.f;
      float iz = (sv.z > 0.f) ? 1.f/sv.z : 0.f;
      float iw = (sv.w > 0.f) ? 1.f/sv.w : 0.f;
      u16* row = wnb + (size_t)d*128;
      row[      lane] = f2bf(w4.x*ix);
      row[ 32 + lane] = f2bf(w4.y*iy);
      row[ 64 + lane] = f2bf(w4.z*iz);
      row[ 96 + lane] = f2bf(w4.w*iw);
    }
  }
}

// ---------------- MFMA GEMM ----------------
template<bool TWO>
__global__ __launch_bounds__(256) void k_mfma(
    const u32* __restrict__ Xb, const u16* __restrict__ wpS, const u16* __restrict__ wpD,
    u16* __restrict__ outS, u16* __restrict__ outD, int N){
  int t = threadIdx.x;
  int w = t >> 6, l = t & 63;
  int row0 = blockIdx.x*64 + w*16;
  int ar = row0 + (l & 15);
  int ko = l >> 4;
  const uint4* Xq = reinterpret_cast<const uint4*>(Xb);
  bf16x8 a[4];
  #pragma unroll
  for (int kb=0;kb<4;++kb){
    if (ar < N) a[kb] = ld_frag(&Xq[(size_t)ar*16 + kb*4 + ko]);
    else { uint4 z = make_uint4(0,0,0,0); __builtin_memcpy(&a[kb], &z, 16); }
  }
  const uint4* WS = reinterpret_cast<const uint4*>(wpS);
  const uint4* WD = reinterpret_cast<const uint4*>(wpD);
  int col0 = l & 15;
  int rbase = row0 + (l>>4)*4;
  #pragma unroll
  for (int nt=0; nt<8; ++nt){
    f32x4 accS = {0.f,0.f,0.f,0.f};
    f32x4 accD = {0.f,0.f,0.f,0.f};
    #pragma unroll
    for (int kb=0;kb<4;++kb){
      bf16x8 bS = ld_frag(&WS[(nt*4 + kb)*64 + l]);
      accS = __builtin_amdgcn_mfma_f32_16x16x32_bf16(a[kb], bS, accS, 0,0,0);
      if (TWO){
        bf16x8 bD = ld_frag(&WD[(nt*4 + kb)*64 + l]);
        accD = __builtin_amdgcn_mfma_f32_16x16x32_bf16(a[kb], bD, accD, 0,0,0);
      }
    }
    int col = nt*16 + col0;
    #pragma unroll
    for (int r=0;r<4;++r){
      int rr = rbase + r;
      if (rr < N){
        outS[(size_t)rr*128 + col] = f2bf(accS[r]);
        if (TWO) outD[(size_t)rr*128 + col] = f2bf(accD[r]);
      }
    }
  }
}

// ---------------- MFMA layer-1: h1 = elu(Wn @ Bts + b1), bf16 out ----------------
__global__ __launch_bounds__(256) void k_mfma1(
    const u32* __restrict__ Xb, const u16* __restrict__ tp, const float* __restrict__ pr,
    u16* __restrict__ outB, int N){
  const float* b1 = pr + 36992;
  int t = threadIdx.x;
  int w = t >> 6, l = t & 63;
  int row0 = blockIdx.x*64 + w*16;
  int ar = row0 + (l & 15);
  int ko = l >> 4;
  const uint4* Xq = reinterpret_cast<const uint4*>(Xb);
  bf16x8 a[4];
  #pragma unroll
  for (int kb=0;kb<4;++kb){
    if (ar < N) a[kb] = ld_frag(&Xq[(size_t)ar*16 + kb*4 + ko]);
    else { uint4 z = make_uint4(0,0,0,0); __builtin_memcpy(&a[kb], &z, 16); }
  }
  const uint4* WB = reinterpret_cast<const uint4*>(tp);
  int col0 = l & 15;
  int rbase = row0 + (l>>4)*4;
  #pragma unroll
  for (int nt=0; nt<8; ++nt){
    f32x4 acc = {0.f,0.f,0.f,0.f};
    #pragma unroll
    for (int kb=0;kb<4;++kb){
      bf16x8 b = ld_frag(&WB[(nt*4 + kb)*64 + l]);
      acc = __builtin_amdgcn_mfma_f32_16x16x32_bf16(a[kb], b, acc, 0,0,0);
    }
    int col = nt*16 + col0;
    float bv = b1[col];
    #pragma unroll
    for (int r=0;r<4;++r){
      int rr = rbase + r;
      if (rr < N) outB[(size_t)rr*128 + col] = f2bf(eluf(acc[r] + bv));
    }
  }
}

// unpack one uint4 (8 bf16) into fv[8]
#define UNPACK8(pv, fv)                                              \
  { float2 _p0 = bfpair(pv.x), _p1 = bfpair(pv.y),                   \
           _p2 = bfpair(pv.z), _p3 = bfpair(pv.w);                   \
    fv[0]=_p0.x; fv[1]=_p0.y; fv[2]=_p1.x; fv[3]=_p1.y;              \
    fv[4]=_p2.x; fv[5]=_p2.y; fv[6]=_p3.x; fv[7]=_p3.y; }

// ---------------- per-node a2-dots for layer 2 (el2/er2) ----------------
__global__ void k_el2(const u32* __restrict__ fsb, const u32* __restrict__ fdb,
                      const float* __restrict__ pr,
                      float* __restrict__ el2, float* __restrict__ er2, int N){
  const float* a2 = pr + 69888;
  int g = blockIdx.x*256 + threadIdx.x;
  if (g >= N*4) return;
  int n = g >> 2, h = g & 3;
  const uint4* fs4 = reinterpret_cast<const uint4*>(fsb) + (size_t)n*16 + h*4;
  const uint4* fd4 = reinterpret_cast<const uint4*>(fdb) + (size_t)n*16 + h*4;
  float aS=0.f, aD=0.f;
  #pragma unroll
  for (int q=0;q<4;++q){
    uint4 ps = fs4[q];
    uint4 pd = fd4[q];
    float fs[8], fd[8];
    UNPACK8(ps, fs);
    UNPACK8(pd, fd);
    const float* ap = a2 + h*32 + q*8;
    #pragma unroll
    for (int k=0;k<8;++k){
      aS = fmaf(ap[k], fs[k], aS);
      aD = fmaf(ap[k], fd[k], aD);
    }
  }
  el2[g] = aS; er2[g] = aD;
}

// ---------------- node2 fused: precomputed linear score + raw exp ----------------
__global__ __launch_bounds__(256) void k_node2f(
    const int* __restrict__ rowptr, const int* __restrict__ esrc,
    const u32* __restrict__ fsb, const u32* __restrict__ fdb,
    const float* __restrict__ el2, const float* __restrict__ er2,
    const float* __restrict__ pr, u32* __restrict__ hOutB, int N){
  const float* a2 = pr + 69888;
  const float* b2 = pr + 70016;
  int t = threadIdx.x;
  int wid = t >> 6, lane = t & 63;
  int q = lane & 15, g = lane >> 4;
  int hh = q >> 2;                  // head of this lane's dims
  int d = blockIdx.x*4 + wid;
  if (d >= N) return;
  int r0 = rowptr[d], r1 = rowptr[d+1];
  const uint4* fs4 = reinterpret_cast<const uint4*>(fsb);
  float a2r[8], fdr[8];
  {
    float4 t0 = *reinterpret_cast<const float4*>(a2 + q*8);
    float4 t1 = *reinterpret_cast<const float4*>(a2 + q*8 + 4);
    a2r[0]=t0.x; a2r[1]=t0.y; a2r[2]=t0.z; a2r[3]=t0.w;
    a2r[4]=t1.x; a2r[5]=t1.y; a2r[6]=t1.z; a2r[7]=t1.w;
    uint4 pv = reinterpret_cast<const uint4*>(fdb)[(size_t)d*16 + q];
    UNPACK8(pv, fdr);
  }
  float er2d = er2[(size_t)d*4 + hh];
  float ssum = 0.f;
  float acc[8] = {0.f,0.f,0.f,0.f,0.f,0.f,0.f,0.f};
  int i = r0 + g;
  for (; i + 4 < r1; i += 8){
    int s1 = esrc[i], s2 = esrc[i+4];
    uint4 pv1 = fs4[(size_t)s1*16 + q];
    uint4 pv2 = fs4[(size_t)s2*16 + q];
    float pl1 = el2[(size_t)s1*4 + hh] + er2d;
    float pl2 = el2[(size_t)s2*4 + hh] + er2d;
    float f1[8], f2[8];
    UNPACK8(pv1, f1);
    UNPACK8(pv2, f2);
    float pb1 = 0.f, pb2 = 0.f;
    #pragma unroll
    for (int k=0;k<8;++k){
      pb1 = fmaf(a2r[k], fabsf(f1[k] + fdr[k]), pb1);
      pb2 = fmaf(a2r[k], fabsf(f2[k] + fdr[k]), pb2);
    }
    pb1 += __shfl_xor(pb1, 1); pb1 += __shfl_xor(pb1, 2);
    pb2 += __shfl_xor(pb2, 1); pb2 += __shfl_xor(pb2, 2);
    float w1 = __expf(fmaf(0.6f, pl1, 0.4f*pb1));
    float w2 = __expf(fmaf(0.6f, pl2, 0.4f*pb2));
    ssum += w1 + w2;
    #pragma unroll
    for (int k=0;k<8;++k) acc[k] = fmaf(w1, f1[k], fmaf(w2, f2[k], acc[k]));
  }
  for (; i < r1; i += 4){
    int s = esrc[i];
    uint4 pv = fs4[(size_t)s*16 + q];
    float pl = el2[(size_t)s*4 + hh] + er2d;
    float fv[8];
    UNPACK8(pv, fv);
    float pb = 0.f;
    #pragma unroll
    for (int k=0;k<8;++k) pb = fmaf(a2r[k], fabsf(fv[k] + fdr[k]), pb);
    pb += __shfl_xor(pb, 1); pb += __shfl_xor(pb, 2);
    float w = __expf(fmaf(0.6f, pl, 0.4f*pb));
    ssum += w;
    #pragma unroll
    for (int k=0;k<8;++k) acc[k] = fmaf(w, fv[k], acc[k]);
  }
  // merge the 4 groups: plain sums (no max state)
  #pragma unroll
  for (int off = 16; off <= 32; off <<= 1){
    ssum += __shfl_xor(ssum, off);
    #pragma unroll
    for (int k=0;k<8;++k) acc[k] += __shfl_xor(acc[k], off);
  }
  if (g == 0){
    float inv = (ssum > 0.f) ? 1.f/ssum : 0.f;
    float v0 = eluf(acc[0]*inv + b2[q*8+0]), v1 = eluf(acc[1]*inv + b2[q*8+1]);
    float v2 = eluf(acc[2]*inv + b2[q*8+2]), v3 = eluf(acc[3]*inv + b2[q*8+3]);
    float v4 = eluf(acc[4]*inv + b2[q*8+4]), v5 = eluf(acc[5]*inv + b2[q*8+5]);
    float v6 = eluf(acc[6]*inv + b2[q*8+6]), v7 = eluf(acc[7]*inv + b2[q*8+7]);
    uint4 ov;
    ov.x = pack2(v0,v1); ov.y = pack2(v2,v3);
    ov.z = pack2(v4,v5); ov.w = pack2(v6,v7);
    *reinterpret_cast<uint4*>(hOutB + (size_t)d*64 + q*4) = ov;
  }
}

// ---------------- node3 fused: raw exp + head mean + final softmax ----------------
__global__ __launch_bounds__(256) void k_node3f(
    const int* __restrict__ rowptr, const int* __restrict__ esrc,
    const float* __restrict__ el, const float* __restrict__ er, const u32* __restrict__ fb,
    const float* __restrict__ pr, const int* __restrict__ flag,
    void* __restrict__ out, int N){
  const float* bc = pr + 86784;
  int t = threadIdx.x;
  int wid = t >> 6, lane = t & 63;
  int q = lane & 15, g = lane >> 4;
  int h = q >> 2;
  int d = blockIdx.x*4 + wid;
  if (d >= N) return;
  int r0 = rowptr[d], r1 = rowptr[d+1];
  const uint4* f4g = reinterpret_cast<const uint4*>(fb);
  float erh = er[(size_t)d*4 + h];
  float ssum = 0.f;
  float acc[8] = {0.f,0.f,0.f,0.f,0.f,0.f,0.f,0.f};
  int i = r0 + g;
  for (; i + 4 < r1; i += 8){
    int s1 = esrc[i], s2 = esrc[i+4];
    float w1 = __expf(lrelu(el[(size_t)s1*4 + h] + erh));
    float w2 = __expf(lrelu(el[(size_t)s2*4 + h] + erh));
    uint4 pv1 = f4g[(size_t)s1*16 + q];
    uint4 pv2 = f4g[(size_t)s2*16 + q];
    float f1[8], f2[8];
    UNPACK8(pv1, f1);
    UNPACK8(pv2, f2);
    ssum += w1 + w2;
    #pragma unroll
    for (int k=0;k<8;++k) acc[k] = fmaf(w1, f1[k], fmaf(w2, f2[k], acc[k]));
  }
  for (; i < r1; i += 4){
    int s = esrc[i];
    float w = __expf(lrelu(el[(size_t)s*4 + h] + erh));
    uint4 pv = f4g[(size_t)s*16 + q];
    float fv[8];
    UNPACK8(pv, fv);
    ssum += w;
    #pragma unroll
    for (int k=0;k<8;++k) acc[k] = fmaf(w, fv[k], acc[k]);
  }
  #pragma unroll
  for (int off = 16; off <= 32; off <<= 1){
    ssum += __shfl_xor(ssum, off);
    #pragma unroll
    for (int k=0;k<8;++k) acc[k] += __shfl_xor(acc[k], off);
  }
  float inv = (ssum > 0.f) ? 1.f/ssum : 0.f;
  float v[8];
  #pragma unroll
  for (int k=0;k<8;++k) v[k] = acc[k]*inv + bc[q*8+k];
  #pragma unroll
  for (int k=0;k<8;++k){
    v[k] += __shfl_xor(v[k], 4);
    v[k] += __shfl_xor(v[k], 8);
    v[k] *= 0.25f;
  }
  float mm = fmaxf(fmaxf(fmaxf(v[0],v[1]),fmaxf(v[2],v[3])),
                   fmaxf(fmaxf(v[4],v[5]),fmaxf(v[6],v[7])));
  mm = fmaxf(mm, __shfl_xor(mm, 1));
  mm = fmaxf(mm, __shfl_xor(mm, 2));
  float ex[8]; float se = 0.f;
  #pragma unroll
  for (int k=0;k<8;++k){ ex[k] = __expf(v[k]-mm); se += ex[k]; }
  se += __shfl_xor(se, 1);
  se += __shfl_xor(se, 2);
  float rs = 1.f/se;
  if (lane < 4){
    if (flag[0]){
      float4 o0 = make_float4(ex[0]*rs, ex[1]*rs, ex[2]*rs, ex[3]*rs);
      float4 o1 = make_float4(ex[4]*rs, ex[5]*rs, ex[6]*rs, ex[7]*rs);
      *reinterpret_cast<float4*>((float*)out + (size_t)d*32 + q*8)     = o0;
      *reinterpret_cast<float4*>((float*)out + (size_t)d*32 + q*8 + 4) = o1;
    } else {
      u32* o = (u32*)out + (size_t)d*16 + q*4;
      o[0] = pack2(ex[0]*rs, ex[1]*rs);
      o[1] = pack2(ex[2]*rs, ex[3]*rs);
      o[2] = pack2(ex[4]*rs, ex[5]*rs);
      o[3] = pack2(ex[6]*rs, ex[7]*rs);
    }
  }
}

// ---------------- per-node el/er for GAT v1 (bf16 input) ----------------
__global__ void k_el(const u32* __restrict__ fb, const float* __restrict__ pr,
                     float* __restrict__ el, float* __restrict__ er, int N){
  const float* al = pr + 86528;
  const float* ar = pr + 86656;
  int g = blockIdx.x*256 + threadIdx.x;
  if (g >= N*4) return;
  int n = g >> 2, h = g & 3;
  const uint4* f4 = reinterpret_cast<const uint4*>(fb) + (size_t)n*16 + h*4;
  float aL=0.f, aR=0.f;
  #pragma unroll
  for (int q=0;q<4;++q){
    uint4 pv = f4[q];
    float fv[8];
    UNPACK8(pv, fv);
    const float* alp = al + h*32 + q*8;
    const float* arp = ar + h*32 + q*8;
    #pragma unroll
    for (int k=0;k<8;++k){
      aL += alp[k]*fv[k];
      aR += arp[k]*fv[k];
    }
  }
  el[g] = aL; er[g] = aR;
}

extern "C" void kernel_launch(void* const* d_in, const int* in_sizes, int n_in,
                              void* d_out, int out_size, void* d_ws, size_t ws_size,
                              hipStream_t stream){
  const int* in_feat = (const int*)d_in[0];
  const int* src     = (const int*)d_in[1];
  const int* dstA    = (const int*)d_in[2];
  const int N = in_sizes[0];
  const int E = in_sizes[1];

  char* p = (char*)d_ws;
  auto alloc = [&](size_t bytes)->char*{
    char* r = p; p += (bytes + 255) & ~(size_t)255; return r;
  };
  float* big0   = (float*)alloc((size_t)N*128*4);   // H, then fs2b (bf16), then f3b (bf16)
  float* big1   = (float*)alloc((size_t)N*128*4);   // bucketBuf, then fd2b (bf16)
  float* big2   = (float*)alloc((size_t)N*128*4);   // h1b+wnb (bf16), then h2b
  int*   deg    = (int*)alloc((size_t)N*4);
  int*   rowptr = (int*)alloc((size_t)(N+1)*4);
  int*   bsum   = (int*)alloc(1024*4);
  int*   boff   = (int*)alloc(1024*4);
  int*   esrc   = (int*)alloc((size_t)E*4);
  int*   gcnt   = (int*)alloc(256*4);
  float* Ts     = (float*)alloc(4096*4);
  float* Td     = (float*)alloc(4096*4);
  float* S1     = (float*)alloc(4096*4);
  float* Ee     = (float*)alloc(4096*4);
  float* el     = (float*)alloc((size_t)N*4*4);
  float* er     = (float*)alloc((size_t)N*4*4);
  float* el2    = (float*)alloc((size_t)N*4*4);
  float* er2    = (float*)alloc((size_t)N*4*4);
  float* parena = (float*)alloc(86912*4);
  u16*   wpack  = (u16*)alloc(4*16384*2);
  int*   flag   = (int*)alloc(256);

  u32* H    = (u32*)big0;
  u32* bbuf = (u32*)big1;
  u16* tpack = wpack + 3*16384;

  // dtype probe + param conversion
  k_probe<<<1,64,0,stream>>>((const u16*)d_in[4], flag);
  Params13 P;
  const int sz[13]  = {4096,16384,16384,128,128,16384,16384,128,128,16384,128,128,128};
  int off = 0;
  for (int t = 0; t < 13; ++t){
    P.src[t] = d_in[3 + t];
    P.n[t] = sz[t];
    P.off[t] = off;
    off += sz[t];
  }
  k_cvt<<<dim3(64,13),256,0,stream>>>(P, flag, parena);
  k_wprep<<<192,256,0,stream>>>(parena, wpack);

  // bucketed CSR build
  int nbkt = (N + 255)/256;
  hipMemsetAsync(gcnt, 0, 256*4, stream);
  int gBin = (E + 2047)/2048;
  k_bin<<<gBin,256,0,stream>>>(src, dstA, in_feat, gcnt, bbuf, E);
  k_bcnt<<<nbkt,256,0,stream>>>(bbuf, gcnt, H, deg, N);
  int nb = (N + 255)/256;
  k_bsum<<<nb,256,0,stream>>>(deg, bsum, N);
  k_scanb<<<1,64,0,stream>>>(bsum, boff, rowptr, nb, N);
  k_scan2<<<nb,256,0,stream>>>(deg, boff, rowptr, N);
  k_csort<<<nbkt,256,0,stream>>>(bbuf, gcnt, rowptr, esrc, N);

  k_tinyA<<<16,256,0,stream>>>(parena, Ts, Td);
  k_tinyB<<<16,256,0,stream>>>(Ts, Td, parena, S1);
  k_tinyC<<<16,256,0,stream>>>(S1, Ee);
  k_t1prep<<<64,256,0,stream>>>(Ts, tpack);

  // layer 1: weights + MFMA with elu epilogue
  u16* h1b = (u16*)big2;
  u16* wnb = (u16*)big2 + (size_t)N*128;
  int gN32 = (N + 31)/32;
  k_node1w<<<gN32,256,0,stream>>>(H, in_feat, Ee, wnb, N);
  int gG = (N + 63)/64;
  k_mfma1<<<gG,256,0,stream>>>((u32*)wnb, tpack, parena, h1b, N);

  u16* fs2b = (u16*)big0;
  u16* fd2b = (u16*)big1;
  k_mfma<true><<<gG,256,0,stream>>>((u32*)h1b, wpack, wpack + 16384, fs2b, fd2b, N);

  int gEl = (int)(((size_t)N*4 + 255)/256);
  k_el2<<<gEl,256,0,stream>>>((u32*)fs2b, (u32*)fd2b, parena, el2, er2, N);

  int gN4 = (N + 3)/4;
  u32* h2b = (u32*)big2;
  k_node2f<<<gN4,256,0,stream>>>(rowptr, esrc, (u32*)fs2b, (u32*)fd2b, el2, er2, parena, h2b, N);

  u16* f3b = (u16*)big0;
  k_mfma<false><<<gG,256,0,stream>>>(h2b, wpack + 32768, nullptr, f3b, nullptr, N);

  k_el<<<gEl,256,0,stream>>>((u32*)f3b, parena, el, er, N);

  k_node3f<<<gN4,256,0,stream>>>(rowptr, esrc, el, er, (u32*)f3b, parena, flag, d_out, N);
}

// Round 15
// 231.411 us; speedup vs baseline: 1.0187x; 1.0187x over previous
//
#include <hip/hip_runtime.h>
#include <hip/hip_bf16.h>

typedef unsigned short u16;
typedef unsigned int u32;

typedef __bf16 bf16x8 __attribute__((ext_vector_type(8)));
typedef float f32x4 __attribute__((ext_vector_type(4)));

#define NEG_SLOPE 0.2f
#define CAP 5120

__device__ __forceinline__ float bf2f(u16 u){
  union { u32 i; float f; } c; c.i = ((u32)u) << 16; return c.f;
}
__device__ __forceinline__ u16 f2bf(float f){
  __hip_bfloat16 h = __float2bfloat16(f);
  u16 u; __builtin_memcpy(&u, &h, 2); return u;
}
__device__ __forceinline__ u32 pack2(float a, float b){
  return (u32)f2bf(a) | ((u32)f2bf(b) << 16);
}
__device__ __forceinline__ float2 bfpair(u32 v){
  union { u32 i; float f; } a, b;
  a.i = v << 16; b.i = v & 0xffff0000u;
  return make_float2(a.f, b.f);
}
__device__ __forceinline__ float lrelu(float x){
  return fmaxf(x, 0.f) + NEG_SLOPE * fminf(x, 0.f);
}
__device__ __forceinline__ float eluf(float x){
  return x > 0.f ? x : (__expf(x) - 1.f);
}
__device__ __forceinline__ bf16x8 ld_frag(const uint4* p){
  uint4 u = *p;
  bf16x8 r;
  __builtin_memcpy(&r, &u, 16);
  return r;
}

// ---------------- dtype probe ----------------
__global__ void k_probe(const u16* __restrict__ w, int* __restrict__ flag){
  int t = threadIdx.x;
  int hit = 0;
  for (int i = t; i < 4096; i += 64){
    u16 v = w[i];
    int e = (v >> 7) & 0xFF;
    if (e >= 200) hit = 1;
  }
  unsigned long long b = __ballot(hit);
  if (t == 0) flag[0] = b ? 1 : 0;   // 1 => float32 data
}

// ---------------- param conversion to f32 arena ----------------
struct Params13 {
  const void* src[13];
  int off[13];
  int n[13];
};

__global__ void k_cvt(Params13 P, const int* __restrict__ flag, float* __restrict__ dst){
  int t = blockIdx.y;
  int i = blockIdx.x*256 + threadIdx.x;
  if (i >= P.n[t]) return;
  int f = flag[0];
  float v = f ? ((const float*)P.src[t])[i] : bf2f(((const u16*)P.src[t])[i]);
  dst[P.off[t] + i] = v;
}

// ---------------- pre-pack W2s/W2d/Wc into MFMA B-fragment order (bf16) ----------------
__global__ void k_wprep(const float* __restrict__ pr, u16* __restrict__ wp){
  int g = blockIdx.x*256 + threadIdx.x;   // 0..49151
  if (g >= 3*16384) return;
  int m = g >> 14;
  int e = g & 16383;
  int j    = e & 7;
  int lane = (e >> 3) & 63;
  int kb   = (e >> 9) & 3;
  int nt   = (e >> 11) & 7;
  int k = kb*32 + (lane >> 4)*8 + j;
  int n = nt*16 + (lane & 15);
  const int Woff[3] = {37120, 53504, 70144};
  wp[g] = f2bf(pr[Woff[m] + k*128 + n]);
}

// pack block-diagonal B from Ts: B[h*32+v][h'*32+dd] = (h==h') ? Ts[v][h'*32+dd] : 0
__global__ void k_t1prep(const float* __restrict__ Ts, u16* __restrict__ tp){
  int g = blockIdx.x*256 + threadIdx.x;   // 0..16383
  if (g >= 16384) return;
  int j    = g & 7;
  int lane = (g >> 3) & 63;
  int kb   = (g >> 9) & 3;
  int nt   = (g >> 11) & 7;
  int k = kb*32 + (lane >> 4)*8 + j;
  int n = nt*16 + (lane & 15);
  int h = k >> 5, hp = n >> 5, v = k & 31;
  tp[g] = (h == hp) ? f2bf(Ts[v*128 + n]) : (u16)0;
}

// ---------------- bucketed CSR build ----------------
__global__ __launch_bounds__(256) void k_bin(
    const int* __restrict__ src, const int* __restrict__ dst, const int* __restrict__ vf,
    int* __restrict__ gcnt, u32* __restrict__ bbuf, int E){
  __shared__ int lcnt[256];
  __shared__ int lloc[256];
  int t = threadIdx.x;
  lcnt[t] = 0;
  __syncthreads();
  int base = blockIdx.x*2048;
  int s[8], d[8];
  #pragma unroll
  for (int k=0;k<8;++k){
    int i = base + k*256 + t;
    if (i < E){ s[k]=src[i]; d[k]=dst[i]; atomicAdd(&lcnt[d[k]>>8], 1); }
    else s[k] = -1;
  }
  __syncthreads();
  if (lcnt[t] > 0) lloc[t] = atomicAdd(&gcnt[t], lcnt[t]);
  __syncthreads();
  #pragma unroll
  for (int k=0;k<8;++k){
    if (s[k] >= 0){
      int b = d[k]>>8;
      int pos = atomicAdd(&lloc[b], 1);
      if (pos < CAP)
        bbuf[(size_t)b*CAP + pos] = ((u32)s[k]<<13) | ((u32)vf[s[k]]<<8) | (u32)(d[k]&255);
    }
  }
}

__global__ __launch_bounds__(256) void k_bcnt(
    const u32* __restrict__ bbuf, const int* __restrict__ gcnt,
    u32* __restrict__ H, int* __restrict__ deg, int N){
  __shared__ u32 lh[8192];   // 256 nodes x 32 types
  __shared__ int ldeg[256];
  int b = blockIdx.x;
  int t = threadIdx.x;
  for (int i=t;i<8192;i+=256) lh[i]=0;
  ldeg[t]=0;
  __syncthreads();
  int n = gcnt[b]; if (n > CAP) n = CAP;
  const u32* bb = bbuf + (size_t)b*CAP;
  for (int i=t;i<n;i+=256){
    u32 it = bb[i];
    int ld = it & 255, v = (it>>8)&31;
    atomicAdd(&lh[ld*32+v], 1u);
    atomicAdd(&ldeg[ld], 1);
  }
  __syncthreads();
  int node0 = b*256;
  for (int i=t;i<8192;i+=256){
    int ld = i>>5;
    if (node0+ld < N) H[(size_t)(node0+ld)*32 + (i&31)] = lh[i];
  }
  if (node0+t < N) deg[node0+t] = ldeg[t];
}

__global__ __launch_bounds__(256) void k_csort(
    const u32* __restrict__ bbuf, const int* __restrict__ gcnt,
    const int* __restrict__ rowptr, int* __restrict__ esrc, int N){
  __shared__ int cur[256];
  int b = blockIdx.x;
  int t = threadIdx.x;
  int node0 = b*256;
  cur[t] = (node0+t < N) ? rowptr[node0+t] : 0;
  __syncthreads();
  int n = gcnt[b]; if (n > CAP) n = CAP;
  const u32* bb = bbuf + (size_t)b*CAP;
  for (int i=t;i<n;i+=256){
    u32 it = bb[i];
    int ld = it & 255;
    int pos = atomicAdd(&cur[ld], 1);
    esrc[pos] = (int)(it >> 13);
  }
}

// ---------------- scan (deg -> rowptr) ----------------
__global__ __launch_bounds__(256) void k_bsum(const int* __restrict__ deg,
                                              int* __restrict__ bsum, int N){
  __shared__ int ws[4];
  int t = threadIdx.x;
  int i = blockIdx.x*256 + t;
  int v = (i < N) ? deg[i] : 0;
  #pragma unroll
  for (int off=32; off>=1; off>>=1) v += __shfl_down(v, off);
  if ((t & 63) == 0) ws[t>>6] = v;
  __syncthreads();
  if (t == 0) bsum[blockIdx.x] = ws[0]+ws[1]+ws[2]+ws[3];
}

__global__ void k_scanb(const int* __restrict__ bsum, int* __restrict__ boff,
                        int* __restrict__ rowptr, int nb, int N){
  int l = threadIdx.x;
  int carry = 0;
  int nChunk = (nb + 63) >> 6;
  for (int c = 0; c < nChunk; ++c){
    int idx = (c << 6) + l;
    int v = (idx < nb) ? bsum[idx] : 0;
    int x = v;
    #pragma unroll
    for (int off=1; off<64; off<<=1){
      int y = __shfl_up(x, off);
      if (l >= off) x += y;
    }
    if (idx < nb) boff[idx] = carry + x - v;
    carry += __shfl(x, 63);
  }
  if (l == 0) rowptr[N] = carry;
}

__global__ __launch_bounds__(256) void k_scan2(const int* __restrict__ deg,
                                               const int* __restrict__ boff,
                                               int* __restrict__ rowptr, int N){
  __shared__ int ws[4];
  int t = threadIdx.x;
  int i = blockIdx.x*256 + t;
  int lane = t & 63, wid = t >> 6;
  int v = (i < N) ? deg[i] : 0;
  int x = v;
  #pragma unroll
  for (int off=1; off<64; off<<=1){
    int y = __shfl_up(x, off);
    if (lane >= off) x += y;
  }
  if (lane == 63) ws[wid] = x;
  __syncthreads();
  int woff = 0;
  #pragma unroll
  for (int w=0; w<4; ++w) woff += (w < wid) ? ws[w] : 0;
  int excl = boff[blockIdx.x] + woff + x - v;
  if (i < N) rowptr[i] = excl;
}

// ---------------- layer-1 tiny tables (16 blocks each) ----------------
__global__ void k_tinyA(const float* __restrict__ pr,
                        float* __restrict__ Ts, float* __restrict__ Td){
  const float* emb = pr + 0;
  const float* W1s = pr + 4096;
  const float* W1d = pr + 20480;
  int g = blockIdx.x*256 + threadIdx.x;   // 0..4095
  int v = g >> 7, j = g & 127;
  float as = 0.f, ad = 0.f;
  for (int k = 0; k < 128; ++k){
    float e = emb[v*128 + k];
    as += e * W1s[k*128 + j];
    ad += e * W1d[k*128 + j];
  }
  Ts[g] = as; Td[g] = ad;
}

__global__ void k_tinyB(const float* __restrict__ Ts, const float* __restrict__ Td,
                        const float* __restrict__ pr, float* __restrict__ S1){
  const float* a1 = pr + 36864;
  int g = blockIdx.x*256 + threadIdx.x;   // vd*128 + vs*4 + h
  int vd = g >> 7, vs = (g >> 2) & 31, h = g & 3;
  float acc = 0.f;
  for (int dd = 0; dd < 32; ++dd){
    float x = Ts[vs*128 + h*32 + dd] + Td[vd*128 + h*32 + dd];
    acc += a1[h*32 + dd] * lrelu(x);
  }
  S1[g] = acc;
}

__global__ void k_tinyC(const float* __restrict__ S1, float* __restrict__ Ee){
  int g = blockIdx.x*256 + threadIdx.x;
  int vd = g >> 7, h = g & 3;
  float M = -INFINITY;
  #pragma unroll 8
  for (int vs = 0; vs < 32; ++vs) M = fmaxf(M, S1[vd*128 + vs*4 + h]);
  Ee[g] = __expf(S1[g] - M);
}

// ---------------- node1 weights: Wn[d][h*32+v] = cnt*Ee / sum (bf16) ----------------
__global__ __launch_bounds__(256) void k_node1w(
    const u32* __restrict__ H, const int* __restrict__ vf,
    const float* __restrict__ Ee, u16* __restrict__ wnb, int N){
  int t = threadIdx.x;
  int wid = t >> 6, lane = t & 63;
  int base = blockIdx.x * 32;
  for (int dd = wid; dd < 32; dd += 4){
    int d = base + dd;
    if (d >= N) break;
    int tt = vf[d];
    float4 w4 = make_float4(0.f,0.f,0.f,0.f);
    if (lane < 32){
      float cf = (float)H[(size_t)d*32 + lane];
      const float4 e4 = *reinterpret_cast<const float4*>(Ee + tt*128 + lane*4);
      w4.x = cf*e4.x; w4.y = cf*e4.y; w4.z = cf*e4.z; w4.w = cf*e4.w;
    }
    float4 sv = w4;
    #pragma unroll
    for (int off=1; off<32; off<<=1){
      sv.x += __shfl_xor(sv.x, off);
      sv.y += __shfl_xor(sv.y, off);
      sv.z += __shfl_xor(sv.z, off);
      sv.w += __shfl_xor(sv.w, off);
    }
    if (lane < 32){
      float ix = (sv.x > 0.f) ? 1.f/sv.x : 0.f;
      float iy = (sv.y > 0.f) ? 1.f/sv.y : 0.f;
      float iz = (sv.z > 0.f) ? 1.f/sv.z : 0.f;
      float iw = (sv.w > 0.f) ? 1.f/sv.w : 0.f;
      u16* row = wnb + (size_t)d*128;
      row[      lane] = f2bf(w4.x*ix);
      row[ 32 + lane] = f2bf(w4.y*iy);
      row[ 64 + lane] = f2bf(w4.z*iz);
      row[ 96 + lane] = f2bf(w4.w*iw);
    }
  }
}

// ---------------- MFMA GEMM ----------------
template<bool TWO>
__global__ __launch_bounds__(256) void k_mfma(
    const u32* __restrict__ Xb, const u16* __restrict__ wpS, const u16* __restrict__ wpD,
    u16* __restrict__ outS, u16* __restrict__ outD, int N){
  int t = threadIdx.x;
  int w = t >> 6, l = t & 63;
  int row0 = blockIdx.x*64 + w*16;
  int ar = row0 + (l & 15);
  int ko = l >> 4;
  const uint4* Xq = reinterpret_cast<const uint4*>(Xb);
  bf16x8 a[4];
  #pragma unroll
  for (int kb=0;kb<4;++kb){
    if (ar < N) a[kb] = ld_frag(&Xq[(size_t)ar*16 + kb*4 + ko]);
    else { uint4 z = make_uint4(0,0,0,0); __builtin_memcpy(&a[kb], &z, 16); }
  }
  const uint4* WS = reinterpret_cast<const uint4*>(wpS);
  const uint4* WD = reinterpret_cast<const uint4*>(wpD);
  int col0 = l & 15;
  int rbase = row0 + (l>>4)*4;
  #pragma unroll
  for (int nt=0; nt<8; ++nt){
    f32x4 accS = {0.f,0.f,0.f,0.f};
    f32x4 accD = {0.f,0.f,0.f,0.f};
    #pragma unroll
    for (int kb=0;kb<4;++kb){
      bf16x8 bS = ld_frag(&WS[(nt*4 + kb)*64 + l]);
      accS = __builtin_amdgcn_mfma_f32_16x16x32_bf16(a[kb], bS, accS, 0,0,0);
      if (TWO){
        bf16x8 bD = ld_frag(&WD[(nt*4 + kb)*64 + l]);
        accD = __builtin_amdgcn_mfma_f32_16x16x32_bf16(a[kb], bD, accD, 0,0,0);
      }
    }
    int col = nt*16 + col0;
    #pragma unroll
    for (int r=0;r<4;++r){
      int rr = rbase + r;
      if (rr < N){
        outS[(size_t)rr*128 + col] = f2bf(accS[r]);
        if (TWO) outD[(size_t)rr*128 + col] = f2bf(accD[r]);
      }
    }
  }
}

// ---------------- MFMA layer-1: h1 = elu(Wn @ Bts + b1), bf16 out ----------------
__global__ __launch_bounds__(256) void k_mfma1(
    const u32* __restrict__ Xb, const u16* __restrict__ tp, const float* __restrict__ pr,
    u16* __restrict__ outB, int N){
  const float* b1 = pr + 36992;
  int t = threadIdx.x;
  int w = t >> 6, l = t & 63;
  int row0 = blockIdx.x*64 + w*16;
  int ar = row0 + (l & 15);
  int ko = l >> 4;
  const uint4* Xq = reinterpret_cast<const uint4*>(Xb);
  bf16x8 a[4];
  #pragma unroll
  for (int kb=0;kb<4;++kb){
    if (ar < N) a[kb] = ld_frag(&Xq[(size_t)ar*16 + kb*4 + ko]);
    else { uint4 z = make_uint4(0,0,0,0); __builtin_memcpy(&a[kb], &z, 16); }
  }
  const uint4* WB = reinterpret_cast<const uint4*>(tp);
  int col0 = l & 15;
  int rbase = row0 + (l>>4)*4;
  #pragma unroll
  for (int nt=0; nt<8; ++nt){
    f32x4 acc = {0.f,0.f,0.f,0.f};
    #pragma unroll
    for (int kb=0;kb<4;++kb){
      bf16x8 b = ld_frag(&WB[(nt*4 + kb)*64 + l]);
      acc = __builtin_amdgcn_mfma_f32_16x16x32_bf16(a[kb], b, acc, 0,0,0);
    }
    int col = nt*16 + col0;
    float bv = b1[col];
    #pragma unroll
    for (int r=0;r<4;++r){
      int rr = rbase + r;
      if (rr < N) outB[(size_t)rr*128 + col] = f2bf(eluf(acc[r] + bv));
    }
  }
}

// unpack one uint4 (8 bf16) into fv[8]
#define UNPACK8(pv, fv)                                              \
  { float2 _p0 = bfpair(pv.x), _p1 = bfpair(pv.y),                   \
           _p2 = bfpair(pv.z), _p3 = bfpair(pv.w);                   \
    fv[0]=_p0.x; fv[1]=_p0.y; fv[2]=_p1.x; fv[3]=_p1.y;              \
    fv[4]=_p2.x; fv[5]=_p2.y; fv[6]=_p3.x; fv[7]=_p3.y; }

// ---------------- node2 fused: abs-trick lrelu dot, online softmax ----------------
// lrelu(x) = 0.6x + 0.4|x|  =>  sum a*lrelu(x) = 0.6*dot(a,x) + 0.4*dot(a,|x|)
__global__ __launch_bounds__(256) void k_node2f(
    const int* __restrict__ rowptr, const int* __restrict__ esrc,
    const u32* __restrict__ fsb, const u32* __restrict__ fdb,
    const float* __restrict__ pr, u32* __restrict__ hOutB, int N){
  const float* a2 = pr + 69888;
  const float* b2 = pr + 70016;
  int t = threadIdx.x;
  int wid = t >> 6, lane = t & 63;
  int q = lane & 15, g = lane >> 4;
  int d = blockIdx.x*4 + wid;
  if (d >= N) return;
  int r0 = rowptr[d], r1 = rowptr[d+1];
  const uint4* fs4 = reinterpret_cast<const uint4*>(fsb);
  float a2r[8], fdr[8];
  {
    float4 t0 = *reinterpret_cast<const float4*>(a2 + q*8);
    float4 t1 = *reinterpret_cast<const float4*>(a2 + q*8 + 4);
    a2r[0]=t0.x; a2r[1]=t0.y; a2r[2]=t0.z; a2r[3]=t0.w;
    a2r[4]=t1.x; a2r[5]=t1.y; a2r[6]=t1.z; a2r[7]=t1.w;
    uint4 pv = reinterpret_cast<const uint4*>(fdb)[(size_t)d*16 + q];
    UNPACK8(pv, fdr);
  }
  float m = -INFINITY, ssum = 0.f;
  float acc[8] = {0.f,0.f,0.f,0.f,0.f,0.f,0.f,0.f};
  int i = r0 + g;
  for (; i + 4 < r1; i += 8){
    int s1 = esrc[i], s2 = esrc[i+4];
    uint4 pv1 = fs4[(size_t)s1*16 + q];
    uint4 pv2 = fs4[(size_t)s2*16 + q];
    float f1[8], f2[8];
    UNPACK8(pv1, f1);
    UNPACK8(pv2, f2);
    float p1a = 0.f, p1b = 0.f, p2a = 0.f, p2b = 0.f;
    #pragma unroll
    for (int k=0;k<8;++k){
      float x1 = f1[k] + fdr[k];
      float x2 = f2[k] + fdr[k];
      p1a = fmaf(a2r[k], x1, p1a);
      p1b = fmaf(a2r[k], fabsf(x1), p1b);
      p2a = fmaf(a2r[k], x2, p2a);
      p2b = fmaf(a2r[k], fabsf(x2), p2b);
    }
    float p1 = fmaf(0.6f, p1a, 0.4f*p1b);
    float p2 = fmaf(0.6f, p2a, 0.4f*p2b);
    p1 += __shfl_xor(p1, 1); p1 += __shfl_xor(p1, 2);
    p2 += __shfl_xor(p2, 1); p2 += __shfl_xor(p2, 2);
    float mn = fmaxf(m, fmaxf(p1, p2));
    float cor = __expf(m - mn);
    float w1 = __expf(p1 - mn);
    float w2 = __expf(p2 - mn);
    ssum = ssum*cor + w1 + w2;
    #pragma unroll
    for (int k=0;k<8;++k) acc[k] = fmaf(acc[k], cor, fmaf(w1, f1[k], w2*f2[k]));
    m = mn;
  }
  for (; i < r1; i += 4){
    int s = esrc[i];
    uint4 pv = fs4[(size_t)s*16 + q];
    float fv[8];
    UNPACK8(pv, fv);
    float pa = 0.f, pb = 0.f;
    #pragma unroll
    for (int k=0;k<8;++k){
      float x = fv[k] + fdr[k];
      pa = fmaf(a2r[k], x, pa);
      pb = fmaf(a2r[k], fabsf(x), pb);
    }
    float p = fmaf(0.6f, pa, 0.4f*pb);
    p += __shfl_xor(p, 1); p += __shfl_xor(p, 2);
    float mn = fmaxf(m, p);
    float cor = __expf(m - mn);
    float w = __expf(p - mn);
    ssum = ssum*cor + w;
    #pragma unroll
    for (int k=0;k<8;++k) acc[k] = fmaf(acc[k], cor, w*fv[k]);
    m = mn;
  }
  // merge the 4 groups' online states
  #pragma unroll
  for (int off = 16; off <= 32; off <<= 1){
    float mo  = __shfl_xor(m, off);
    float sso = __shfl_xor(ssum, off);
    float ao[8];
    #pragma unroll
    for (int k=0;k<8;++k) ao[k] = __shfl_xor(acc[k], off);
    float mn = fmaxf(m, mo);
    float c1 = (m  > -1e30f) ? __expf(m  - mn) : 0.f;
    float c2 = (mo > -1e30f) ? __expf(mo - mn) : 0.f;
    ssum = ssum*c1 + sso*c2;
    #pragma unroll
    for (int k=0;k<8;++k) acc[k] = acc[k]*c1 + ao[k]*c2;
    m = mn;
  }
  if (g == 0){
    float inv = (ssum > 0.f) ? 1.f/ssum : 0.f;
    float v0 = eluf(acc[0]*inv + b2[q*8+0]), v1 = eluf(acc[1]*inv + b2[q*8+1]);
    float v2 = eluf(acc[2]*inv + b2[q*8+2]), v3 = eluf(acc[3]*inv + b2[q*8+3]);
    float v4 = eluf(acc[4]*inv + b2[q*8+4]), v5 = eluf(acc[5]*inv + b2[q*8+5]);
    float v6 = eluf(acc[6]*inv + b2[q*8+6]), v7 = eluf(acc[7]*inv + b2[q*8+7]);
    uint4 ov;
    ov.x = pack2(v0,v1); ov.y = pack2(v2,v3);
    ov.z = pack2(v4,v5); ov.w = pack2(v6,v7);
    *reinterpret_cast<uint4*>(hOutB + (size_t)d*64 + q*4) = ov;
  }
}

// ---------------- node3 fused: online softmax + head mean + final softmax ----------------
__global__ __launch_bounds__(256) void k_node3f(
    const int* __restrict__ rowptr, const int* __restrict__ esrc,
    const float* __restrict__ el, const float* __restrict__ er, const u32* __restrict__ fb,
    const float* __restrict__ pr, const int* __restrict__ flag,
    void* __restrict__ out, int N){
  const float* bc = pr + 86784;
  int t = threadIdx.x;
  int wid = t >> 6, lane = t & 63;
  int q = lane & 15, g = lane >> 4;
  int h = q >> 2;
  int d = blockIdx.x*4 + wid;
  if (d >= N) return;
  int r0 = rowptr[d], r1 = rowptr[d+1];
  const uint4* f4g = reinterpret_cast<const uint4*>(fb);
  float erh = er[(size_t)d*4 + h];
  float m = -INFINITY, ssum = 0.f;
  float acc[8] = {0.f,0.f,0.f,0.f,0.f,0.f,0.f,0.f};
  int i = r0 + g;
  for (; i + 4 < r1; i += 8){
    int s1 = esrc[i], s2 = esrc[i+4];
    float sc1 = lrelu(el[(size_t)s1*4 + h] + erh);
    float sc2 = lrelu(el[(size_t)s2*4 + h] + erh);
    uint4 pv1 = f4g[(size_t)s1*16 + q];
    uint4 pv2 = f4g[(size_t)s2*16 + q];
    float f1[8], f2[8];
    UNPACK8(pv1, f1);
    UNPACK8(pv2, f2);
    float mn = fmaxf(m, fmaxf(sc1, sc2));
    float cor = __expf(m - mn);
    float w1 = __expf(sc1 - mn);
    float w2 = __expf(sc2 - mn);
    ssum = ssum*cor + w1 + w2;
    #pragma unroll
    for (int k=0;k<8;++k) acc[k] = fmaf(acc[k], cor, fmaf(w1, f1[k], w2*f2[k]));
    m = mn;
  }
  for (; i < r1; i += 4){
    int s = esrc[i];
    float sc = lrelu(el[(size_t)s*4 + h] + erh);
    uint4 pv = f4g[(size_t)s*16 + q];
    float fv[8];
    UNPACK8(pv, fv);
    float mn = fmaxf(m, sc);
    float cor = __expf(m - mn);
    float w = __expf(sc - mn);
    ssum = ssum*cor + w;
    #pragma unroll
    for (int k=0;k<8;++k) acc[k] = fmaf(acc[k], cor, w*fv[k]);
    m = mn;
  }
  #pragma unroll
  for (int off = 16; off <= 32; off <<= 1){
    float mo  = __shfl_xor(m, off);
    float sso = __shfl_xor(ssum, off);
    float ao[8];
    #pragma unroll
    for (int k=0;k<8;++k) ao[k] = __shfl_xor(acc[k], off);
    float mn = fmaxf(m, mo);
    float c1 = (m  > -1e30f) ? __expf(m  - mn) : 0.f;
    float c2 = (mo > -1e30f) ? __expf(mo - mn) : 0.f;
    ssum = ssum*c1 + sso*c2;
    #pragma unroll
    for (int k=0;k<8;++k) acc[k] = acc[k]*c1 + ao[k]*c2;
    m = mn;
  }
  float inv = (ssum > 0.f) ? 1.f/ssum : 0.f;
  float v[8];
  #pragma unroll
  for (int k=0;k<8;++k) v[k] = acc[k]*inv + bc[q*8+k];
  #pragma unroll
  for (int k=0;k<8;++k){
    v[k] += __shfl_xor(v[k], 4);
    v[k] += __shfl_xor(v[k], 8);
    v[k] *= 0.25f;
  }
  float mm = fmaxf(fmaxf(fmaxf(v[0],v[1]),fmaxf(v[2],v[3])),
                   fmaxf(fmaxf(v[4],v[5]),fmaxf(v[6],v[7])));
  mm = fmaxf(mm, __shfl_xor(mm, 1));
  mm = fmaxf(mm, __shfl_xor(mm, 2));
  float ex[8]; float se = 0.f;
  #pragma unroll
  for (int k=0;k<8;++k){ ex[k] = __expf(v[k]-mm); se += ex[k]; }
  se += __shfl_xor(se, 1);
  se += __shfl_xor(se, 2);
  float rs = 1.f/se;
  if (lane < 4){
    if (flag[0]){
      float4 o0 = make_float4(ex[0]*rs, ex[1]*rs, ex[2]*rs, ex[3]*rs);
      float4 o1 = make_float4(ex[4]*rs, ex[5]*rs, ex[6]*rs, ex[7]*rs);
      *reinterpret_cast<float4*>((float*)out + (size_t)d*32 + q*8)     = o0;
      *reinterpret_cast<float4*>((float*)out + (size_t)d*32 + q*8 + 4) = o1;
    } else {
      u32* o = (u32*)out + (size_t)d*16 + q*4;
      o[0] = pack2(ex[0]*rs, ex[1]*rs);
      o[1] = pack2(ex[2]*rs, ex[3]*rs);
      o[2] = pack2(ex[4]*rs, ex[5]*rs);
      o[3] = pack2(ex[6]*rs, ex[7]*rs);
    }
  }
}

// ---------------- per-node el/er for GAT v1 (bf16 input) ----------------
__global__ void k_el(const u32* __restrict__ fb, const float* __restrict__ pr,
                     float* __restrict__ el, float* __restrict__ er, int N){
  const float* al = pr + 86528;
  const float* ar = pr + 86656;
  int g = blockIdx.x*256 + threadIdx.x;
  if (g >= N*4) return;
  int n = g >> 2, h = g & 3;
  const uint4* f4 = reinterpret_cast<const uint4*>(fb) + (size_t)n*16 + h*4;
  float aL=0.f, aR=0.f;
  #pragma unroll
  for (int q=0;q<4;++q){
    uint4 pv = f4[q];
    float fv[8];
    UNPACK8(pv, fv);
    const float* alp = al + h*32 + q*8;
    const float* arp = ar + h*32 + q*8;
    #pragma unroll
    for (int k=0;k<8;++k){
      aL += alp[k]*fv[k];
      aR += arp[k]*fv[k];
    }
  }
  el[g] = aL; er[g] = aR;
}

extern "C" void kernel_launch(void* const* d_in, const int* in_sizes, int n_in,
                              void* d_out, int out_size, void* d_ws, size_t ws_size,
                              hipStream_t stream){
  const int* in_feat = (const int*)d_in[0];
  const int* src     = (const int*)d_in[1];
  const int* dstA    = (const int*)d_in[2];
  const int N = in_sizes[0];
  const int E = in_sizes[1];

  char* p = (char*)d_ws;
  auto alloc = [&](size_t bytes)->char*{
    char* r = p; p += (bytes + 255) & ~(size_t)255; return r;
  };
  float* big0   = (float*)alloc((size_t)N*128*4);   // H, then fs2b (bf16), then f3b (bf16)
  float* big1   = (float*)alloc((size_t)N*128*4);   // bucketBuf, then fd2b (bf16)
  float* big2   = (float*)alloc((size_t)N*128*4);   // h1b+wnb (bf16), then h2b
  int*   deg    = (int*)alloc((size_t)N*4);
  int*   rowptr = (int*)alloc((size_t)(N+1)*4);
  int*   bsum   = (int*)alloc(1024*4);
  int*   boff   = (int*)alloc(1024*4);
  int*   esrc   = (int*)alloc((size_t)E*4);
  int*   gcnt   = (int*)alloc(256*4);
  float* Ts     = (float*)alloc(4096*4);
  float* Td     = (float*)alloc(4096*4);
  float* S1     = (float*)alloc(4096*4);
  float* Ee     = (float*)alloc(4096*4);
  float* el     = (float*)alloc((size_t)N*4*4);
  float* er     = (float*)alloc((size_t)N*4*4);
  float* parena = (float*)alloc(86912*4);
  u16*   wpack  = (u16*)alloc(4*16384*2);
  int*   flag   = (int*)alloc(256);

  u32* H    = (u32*)big0;
  u32* bbuf = (u32*)big1;
  u16* tpack = wpack + 3*16384;

  // dtype probe + param conversion
  k_probe<<<1,64,0,stream>>>((const u16*)d_in[4], flag);
  Params13 P;
  const int sz[13]  = {4096,16384,16384,128,128,16384,16384,128,128,16384,128,128,128};
  int off = 0;
  for (int t = 0; t < 13; ++t){
    P.src[t] = d_in[3 + t];
    P.n[t] = sz[t];
    P.off[t] = off;
    off += sz[t];
  }
  k_cvt<<<dim3(64,13),256,0,stream>>>(P, flag, parena);
  k_wprep<<<192,256,0,stream>>>(parena, wpack);

  // bucketed CSR build
  int nbkt = (N + 255)/256;
  hipMemsetAsync(gcnt, 0, 256*4, stream);
  int gBin = (E + 2047)/2048;
  k_bin<<<gBin,256,0,stream>>>(src, dstA, in_feat, gcnt, bbuf, E);
  k_bcnt<<<nbkt,256,0,stream>>>(bbuf, gcnt, H, deg, N);
  int nb = (N + 255)/256;
  k_bsum<<<nb,256,0,stream>>>(deg, bsum, N);
  k_scanb<<<1,64,0,stream>>>(bsum, boff, rowptr, nb, N);
  k_scan2<<<nb,256,0,stream>>>(deg, boff, rowptr, N);
  k_csort<<<nbkt,256,0,stream>>>(bbuf, gcnt, rowptr, esrc, N);

  k_tinyA<<<16,256,0,stream>>>(parena, Ts, Td);
  k_tinyB<<<16,256,0,stream>>>(Ts, Td, parena, S1);
  k_tinyC<<<16,256,0,stream>>>(S1, Ee);
  k_t1prep<<<64,256,0,stream>>>(Ts, tpack);

  // layer 1: weights + MFMA with elu epilogue
  u16* h1b = (u16*)big2;
  u16* wnb = (u16*)big2 + (size_t)N*128;
  int gN32 = (N + 31)/32;
  k_node1w<<<gN32,256,0,stream>>>(H, in_feat, Ee, wnb, N);
  int gG = (N + 63)/64;
  k_mfma1<<<gG,256,0,stream>>>((u32*)wnb, tpack, parena, h1b, N);

  u16* fs2b = (u16*)big0;        // overwrites H (dead after node1w)
  u16* fd2b = (u16*)big1;        // overwrites bucketBuf (dead after csort)
  k_mfma<true><<<gG,256,0,stream>>>((u32*)h1b, wpack, wpack + 16384, fs2b, fd2b, N);

  int gN4 = (N + 3)/4;
  u32* h2b = (u32*)big2;         // overwrites h1b (dead after mfma<true>)
  k_node2f<<<gN4,256,0,stream>>>(rowptr, esrc, (u32*)fs2b, (u32*)fd2b, parena, h2b, N);

  u16* f3b = (u16*)big0;         // fs2b dead after node2f
  k_mfma<false><<<gG,256,0,stream>>>(h2b, wpack + 32768, nullptr, f3b, nullptr, N);

  int gEl = (int)(((size_t)N*4 + 255)/256);
  k_el<<<gEl,256,0,stream>>>((u32*)f3b, parena, el, er, N);

  k_node3f<<<gN4,256,0,stream>>>(rowptr, esrc, el, er, (u32*)f3b, parena, flag, d_out, N);
}